// Round 5
// baseline (75.984 us; speedup 1.0000x reference)
//
#include <hip/hip_runtime.h>
#include <hip/hip_bf16.h>
#include <math.h>

#define Bn   16
#define T1n  256
#define T2n  256
#define Dn   256
#define MPn  32

typedef __attribute__((ext_vector_type(8))) short short8;
typedef __attribute__((ext_vector_type(4))) float f32x4;

__device__ inline short f2b(float f) {
  __hip_bfloat16 h = __float2bfloat16(f);
  return __builtin_bit_cast(short, h);
}
__device__ inline float b2f(short s) {
  unsigned int u = ((unsigned int)(unsigned short)s) << 16;
  return __builtin_bit_cast(float, u);
}
__device__ inline float max4(f32x4 a) {
  return fmaxf(fmaxf(a.x, a.y), fmaxf(a.z, a.w));
}

// ---------------- pre-pass: f32 -> bf16 for lt and rt ----------------
__global__ __launch_bounds__(256, 8)
void cvt_bf16_kernel(const float* __restrict__ lt, const float* __restrict__ rt,
                     short* __restrict__ olt, short* __restrict__ ort) {
  int blk = blockIdx.x;
  const float* src;
  short* dst;
  int t;
  if (blk < 512) { src = lt; dst = olt; t = blk * 256 + threadIdx.x; }
  else           { src = rt; dst = ort; t = (blk - 512) * 256 + threadIdx.x; }
  const f32x4* s = reinterpret_cast<const f32x4*>(src + (size_t)t * 8);
  f32x4 f0 = s[0], f1 = s[1];
  short8 v;
  v[0] = f2b(f0.x); v[1] = f2b(f0.y); v[2] = f2b(f0.z); v[3] = f2b(f0.w);
  v[4] = f2b(f1.x); v[5] = f2b(f1.y); v[6] = f2b(f1.z); v[7] = f2b(f1.w);
  *reinterpret_cast<short8*>(dst + (size_t)t * 8) = v;
}

// -------- main: zero LDS, zero barriers; frags direct from L2 --------
// 1024 blocks = b(16) x jblk(8: 32 j) x mg(8: 4 m); 4 waves, wave -> own m.
// All 4 waves of a block read IDENTICAL lt/rt addresses -> L1 dedup.
__global__ __launch_bounds__(256, 4)
void mp_match_kernel(const short* __restrict__ ltb,
                     const short* __restrict__ rtb,
                     const float* __restrict__ kern,
                     float* __restrict__ out) {
  const int bid = blockIdx.x;
  const int xcd = bid & 7;                  // b = xcd or 8+xcd -> L2 locality
  const int idx = bid >> 3;                 // 0..127
  const int b   = ((idx >> 6) << 3) | xcd;
  const int rem = idx & 63;
  const int jblk = rem & 7;
  const int mg   = rem >> 3;
  const int j0   = jblk * 32;

  const int tid  = threadIdx.x;
  const int lane = tid & 63;
  const int w    = tid >> 6;                // wave -> its own m
  const int m    = mg * 4 + w;
  const int bl   = lane & 15;               // fragment row/col
  const int hl   = lane >> 4;               // k-subchunk

  const short* ltbase = ltb + (size_t)b * T1n * Dn;            // wave-uniform
  const short* rtbase = rtb + ((size_t)b * T2n + j0) * Dn;
  const float* kbase  = kern + (size_t)m * Dn;

  const int foff = bl * Dn + hl * 8;        // per-lane fragment offset (elems)

  // ---- B fragments: rt direct from L2, scaled by k[m], kept in regs ----
  short8 bsc[2][8];
  #pragma unroll
  for (int kk = 0; kk < 8; ++kk) {
    const f32x4* kp = reinterpret_cast<const f32x4*>(kbase + (kk * 4 + hl) * 8);
    f32x4 k0 = kp[0], k1 = kp[1];
    #pragma unroll
    for (int sub = 0; sub < 2; ++sub) {
      short8 r = *reinterpret_cast<const short8*>(rtbase + sub * 16 * Dn + foff + kk * 32);
      short8 v;
      v[0] = f2b(b2f(r[0]) * k0.x); v[1] = f2b(b2f(r[1]) * k0.y);
      v[2] = f2b(b2f(r[2]) * k0.z); v[3] = f2b(b2f(r[3]) * k0.w);
      v[4] = f2b(b2f(r[4]) * k1.x); v[5] = f2b(b2f(r[5]) * k1.y);
      v[6] = f2b(b2f(r[6]) * k1.z); v[7] = f2b(b2f(r[7]) * k1.w);
      bsc[sub][kk] = v;
    }
  }

  float jmax0 = -1e30f, jmax1 = -1e30f;

  // ---- 16 chunks of 16 i-rows; A-frags straight from L2 ----
  #pragma unroll 1
  for (int ic = 0; ic < 16; ++ic) {
    const short* abase = ltbase + ic * 16 * Dn + foff;
    f32x4 a0 = {0.f, 0.f, 0.f, 0.f};
    f32x4 a1 = {0.f, 0.f, 0.f, 0.f};
    #pragma unroll
    for (int kk = 0; kk < 8; ++kk) {
      short8 A = *reinterpret_cast<const short8*>(abase + kk * 32);
      a0 = __builtin_amdgcn_mfma_f32_16x16x32_bf16(A, bsc[0][kk], a0, 0, 0, 0);
      a1 = __builtin_amdgcn_mfma_f32_16x16x32_bf16(A, bsc[1][kk], a1, 0, 0, 0);
    }
    jmax0 = fmaxf(jmax0, max4(a0));
    jmax1 = fmaxf(jmax1, max4(a1));
  }

  // ---- cross-lane col-max over the 4 row-groups, tanh, store ----
  jmax0 = fmaxf(jmax0, __shfl_xor(jmax0, 16));
  jmax0 = fmaxf(jmax0, __shfl_xor(jmax0, 32));
  jmax1 = fmaxf(jmax1, __shfl_xor(jmax1, 16));
  jmax1 = fmaxf(jmax1, __shfl_xor(jmax1, 32));
  if (hl < 2) {
    float v = hl ? jmax1 : jmax0;
    int j = j0 + hl * 16 + bl;
    out[((size_t)b * T2n + j) * MPn + m] = tanhf(v);
  }
}

extern "C" void kernel_launch(void* const* d_in, const int* in_sizes, int n_in,
                              void* d_out, int out_size, void* d_ws, size_t ws_size,
                              hipStream_t stream) {
  const float* lt   = (const float*)d_in[0];
  const float* rt   = (const float*)d_in[1];
  const float* kern = (const float*)d_in[2];
  float* out = (float*)d_out;

  short* ltb = (short*)d_ws;                       // 2 MB
  short* rtb = ltb + (size_t)Bn * T1n * Dn;        // 2 MB more

  cvt_bf16_kernel<<<1024, 256, 0, stream>>>(lt, rt, ltb, rtb);
  mp_match_kernel<<<1024, 256, 0, stream>>>(ltb, rtb, kern, out);
}

// Round 6
// 27.210 us; speedup vs baseline: 2.7926x; 2.7926x over previous
//
#include <hip/hip_runtime.h>
#include <hip/hip_bf16.h>
#include <math.h>

#define Bn   16
#define T1n  256
#define T2n  256
#define Dn   256
#define MPn  32

typedef __attribute__((ext_vector_type(8))) short short8;
typedef __attribute__((ext_vector_type(4))) float f32x4;

typedef const __attribute__((address_space(1))) void* gp_t;
typedef __attribute__((address_space(3))) void* lp_t;

__device__ __forceinline__ void gl_lds16(const void* g, void* l) {
  // async global->LDS, 16B/lane; LDS dest = wave-uniform base + lane*16
  __builtin_amdgcn_global_load_lds((gp_t)g, (lp_t)l, 16, 0, 0);
}
__device__ __forceinline__ void fence() { asm volatile("" ::: "memory"); }
__device__ __forceinline__ void bar() {
  fence();
  __builtin_amdgcn_s_barrier();
  fence();
}
#define WAIT_VM(N) asm volatile("s_waitcnt vmcnt(" #N ")" ::: "memory")

__device__ inline short f2b(float f) {
  __hip_bfloat16 h = __float2bfloat16(f);
  return __builtin_bit_cast(short, h);
}
__device__ inline float b2f(short s) {
  unsigned int u = ((unsigned int)(unsigned short)s) << 16;
  return __builtin_bit_cast(float, u);
}
__device__ inline float max4(f32x4 a) {
  return fmaxf(fmaxf(a.x, a.y), fmaxf(a.z, a.w));
}

// swizzled 16B-chunk index within a [rows][256 d] bf16 tile.
// XOR of row&7 spreads stride-512B column reads across 8 16B slots.
// gl_lds source is pre-swizzled with the same XOR (involution), LDS linear.
__device__ inline int swz_chunk(int row, int d8) {
  return row * 32 + (d8 ^ (row & 7));
}

// ---------------- pre-pass: f32 -> bf16 for lt and rt ----------------
__global__ __launch_bounds__(256, 8)
void cvt_bf16_kernel(const float* __restrict__ lt, const float* __restrict__ rt,
                     short* __restrict__ olt, short* __restrict__ ort) {
  int blk = blockIdx.x;
  const float* src;
  short* dst;
  int t;
  if (blk < 512) { src = lt; dst = olt; t = blk * 256 + threadIdx.x; }
  else           { src = rt; dst = ort; t = (blk - 512) * 256 + threadIdx.x; }
  const f32x4* s = reinterpret_cast<const f32x4*>(src + (size_t)t * 8);
  f32x4 f0 = s[0], f1 = s[1];
  short8 v;
  v[0] = f2b(f0.x); v[1] = f2b(f0.y); v[2] = f2b(f0.z); v[3] = f2b(f0.w);
  v[4] = f2b(f1.x); v[5] = f2b(f1.y); v[6] = f2b(f1.z); v[7] = f2b(f1.w);
  *reinterpret_cast<short8*>(dst + (size_t)t * 8) = v;
}

// -------- main: 512 blocks = b(16) x jblk(4: 64j) x mg(8: 4m); 4 waves --------
// Counted-vmcnt double-buffered lt pipeline; raw barriers; no vmcnt(0) in loop.
__global__ __launch_bounds__(256, 2)
void mp_match_kernel(const short* __restrict__ ltb,
                     const short* __restrict__ rtb,
                     const float* __restrict__ kern,
                     float* __restrict__ out) {
  __shared__ short lds_rt[64 * 256];        // 32 KB
  __shared__ short lds_lt[2][32 * 256];     // 32 KB   -> 64 KB total, 2 blk/CU

  const int bid = blockIdx.x;               // 512 blocks
  const int xcd = bid & 7;                  // b = xcd or 8+xcd -> L2 locality
  const int idx = bid >> 3;                 // 0..63
  const int b   = ((idx >> 5) << 3) | xcd;
  const int rem = idx & 31;
  const int jblk = rem & 3;                 // 4 j-blocks of 64
  const int mg   = rem >> 2;                // 8 m-groups of 4
  const int j0   = jblk * 64;

  const int tid  = threadIdx.x;             // 0..255
  const int lane = tid & 63;
  const int w    = tid >> 6;                // wave -> its own m
  const int m    = mg * 4 + w;
  const int bl   = lane & 15;
  const int hl   = lane >> 4;

  const short* lbase = ltb + (size_t)b * T1n * Dn;
  const short* rbase = rtb + ((size_t)b * T2n + j0) * Dn;
  const float* kbase = kern + (size_t)m * Dn;

  // per-thread gl_lds source offsets (pre-swizzled), dest is linear chunk idx
  int soffL[4];                             // lt chunk: [32 rows][256 d]
  #pragma unroll
  for (int it = 0; it < 4; ++it) {
    int cidx = it * 256 + tid;
    int row = cidx >> 5, slot = cidx & 31;
    soffL[it] = row * 256 + (slot ^ (row & 7)) * 8;
  }
  const int wub = (tid & ~63) * 8;          // wave-uniform dest part (shorts)

  // ---- (1) kern f32 loads FIRST (oldest in vmcnt queue) ----
  f32x4 kq[8][2];
  #pragma unroll
  for (int kk = 0; kk < 8; ++kk) {
    const f32x4* kp = reinterpret_cast<const f32x4*>(kbase + (kk * 4 + hl) * 8);
    kq[kk][0] = kp[0];
    kq[kk][1] = kp[1];
  }
  fence();
  // ---- (2) rt tile: [64 rows][256 d], 8 gl_lds/thread ----
  #pragma unroll
  for (int it = 0; it < 8; ++it) {
    int cidx = it * 256 + tid;
    int row = cidx >> 5, slot = cidx & 31;
    gl_lds16(rbase + row * 256 + (slot ^ (row & 7)) * 8,
             &lds_rt[it * 256 * 8 + wub]);
  }
  fence();
  // ---- (3) lt chunk 0 and (4) chunk 1 ----
  #pragma unroll
  for (int it = 0; it < 4; ++it)
    gl_lds16(lbase + soffL[it], &lds_lt[0][it * 256 * 8 + wub]);
  fence();
  #pragma unroll
  for (int it = 0; it < 4; ++it)
    gl_lds16(lbase + 32 * 256 + soffL[it], &lds_lt[1][it * 256 * 8 + wub]);
  fence();

  WAIT_VM(8);                               // kern + rt landed; c0,c1 in flight
  bar();

  // ---- B fragments scaled by k[m] once, kept in regs (128 VGPR) ----
  short8 bsc[4][8];
  #pragma unroll
  for (int kk = 0; kk < 8; ++kk) {
    f32x4 k0 = kq[kk][0], k1 = kq[kk][1];
    #pragma unroll
    for (int sub = 0; sub < 4; ++sub) {
      int brow = sub * 16 + bl;
      short8 r = *reinterpret_cast<const short8*>(
          &lds_rt[swz_chunk(brow, kk * 4 + hl) * 8]);
      short8 v;
      v[0] = f2b(b2f(r[0]) * k0.x); v[1] = f2b(b2f(r[1]) * k0.y);
      v[2] = f2b(b2f(r[2]) * k0.z); v[3] = f2b(b2f(r[3]) * k0.w);
      v[4] = f2b(b2f(r[4]) * k1.x); v[5] = f2b(b2f(r[5]) * k1.y);
      v[6] = f2b(b2f(r[6]) * k1.z); v[7] = f2b(b2f(r[7]) * k1.w);
      bsc[sub][kk] = v;
    }
  }

  WAIT_VM(4);                               // own c0 landed
  bar();                                    // => everyone's c0 landed

  float jmax0 = -1e30f, jmax1 = -1e30f, jmax2 = -1e30f, jmax3 = -1e30f;

  // ---- 8 chunks of 32 i-rows; 2-deep counted-vmcnt pipeline ----
  #pragma unroll 1
  for (int ic = 0; ic < 8; ++ic) {
    const int cur = ic & 1;
    const short* lcur = lds_lt[cur];
    __builtin_amdgcn_s_setprio(1);
    #pragma unroll
    for (int it2 = 0; it2 < 2; ++it2) {
      int arow = it2 * 16 + bl;
      f32x4 a0 = {0.f,0.f,0.f,0.f}, a1 = {0.f,0.f,0.f,0.f};
      f32x4 a2 = {0.f,0.f,0.f,0.f}, a3 = {0.f,0.f,0.f,0.f};
      #pragma unroll
      for (int kk = 0; kk < 8; ++kk) {
        short8 A = *reinterpret_cast<const short8*>(
            &lcur[swz_chunk(arow, kk * 4 + hl) * 8]);
        a0 = __builtin_amdgcn_mfma_f32_16x16x32_bf16(A, bsc[0][kk], a0, 0, 0, 0);
        a1 = __builtin_amdgcn_mfma_f32_16x16x32_bf16(A, bsc[1][kk], a1, 0, 0, 0);
        a2 = __builtin_amdgcn_mfma_f32_16x16x32_bf16(A, bsc[2][kk], a2, 0, 0, 0);
        a3 = __builtin_amdgcn_mfma_f32_16x16x32_bf16(A, bsc[3][kk], a3, 0, 0, 0);
      }
      jmax0 = fmaxf(jmax0, max4(a0));
      jmax1 = fmaxf(jmax1, max4(a1));
      jmax2 = fmaxf(jmax2, max4(a2));
      jmax3 = fmaxf(jmax3, max4(a3));
    }
    __builtin_amdgcn_s_setprio(0);
    bar();                                  // all waves done READING lcur
    if (ic < 6) {
      #pragma unroll
      for (int it = 0; it < 4; ++it)        // re-stage cur <- chunk ic+2
        gl_lds16(lbase + (ic + 2) * 32 * 256 + soffL[it],
                 &lds_lt[cur][it * 256 * 8 + wub]);
      fence();
      WAIT_VM(4);                           // own (ic+1) loads landed
      bar();                                // => everyone's (ic+1) landed
    } else if (ic == 6) {
      WAIT_VM(0);                           // tail: c7 landed
      bar();
    }
  }

  // ---- cross-lane col-max over the 4 row-groups, tanh, store ----
  jmax0 = fmaxf(jmax0, __shfl_xor(jmax0, 16));
  jmax0 = fmaxf(jmax0, __shfl_xor(jmax0, 32));
  jmax1 = fmaxf(jmax1, __shfl_xor(jmax1, 16));
  jmax1 = fmaxf(jmax1, __shfl_xor(jmax1, 32));
  jmax2 = fmaxf(jmax2, __shfl_xor(jmax2, 16));
  jmax2 = fmaxf(jmax2, __shfl_xor(jmax2, 32));
  jmax3 = fmaxf(jmax3, __shfl_xor(jmax3, 16));
  jmax3 = fmaxf(jmax3, __shfl_xor(jmax3, 32));
  // every lane stores one output: j-subtile picked by hl, col by bl
  float v = (hl == 0) ? jmax0 : (hl == 1) ? jmax1 : (hl == 2) ? jmax2 : jmax3;
  int j = j0 + hl * 16 + bl;
  out[((size_t)b * T2n + j) * MPn + m] = tanhf(v);
}

extern "C" void kernel_launch(void* const* d_in, const int* in_sizes, int n_in,
                              void* d_out, int out_size, void* d_ws, size_t ws_size,
                              hipStream_t stream) {
  const float* lt   = (const float*)d_in[0];
  const float* rt   = (const float*)d_in[1];
  const float* kern = (const float*)d_in[2];
  float* out = (float*)d_out;

  short* ltb = (short*)d_ws;                       // 2 MB
  short* rtb = ltb + (size_t)Bn * T1n * Dn;        // 2 MB more

  cvt_bf16_kernel<<<1024, 256, 0, stream>>>(lt, rt, ltb, rtb);
  mp_match_kernel<<<512, 256, 0, stream>>>(ltb, rtb, kern, out);
}

// Round 7
// 26.803 us; speedup vs baseline: 2.8349x; 1.0152x over previous
//
#include <hip/hip_runtime.h>
#include <hip/hip_bf16.h>
#include <math.h>

#define Bn   16
#define T1n  256
#define T2n  256
#define Dn   256
#define MPn  32

typedef __attribute__((ext_vector_type(8)))  short short8;
typedef __attribute__((ext_vector_type(4)))  float f32x4;
typedef __attribute__((ext_vector_type(16))) float f32x16;

__device__ inline short f2b(float f) {
  __hip_bfloat16 h = __float2bfloat16(f);
  return __builtin_bit_cast(short, h);
}
__device__ inline float b2f(short s) {
  unsigned int u = ((unsigned int)(unsigned short)s) << 16;
  return __builtin_bit_cast(float, u);
}

// swizzled 16B-chunk index within a [64 row][256 d] bf16 tile.
// XOR of row&7 spreads stride-512B column reads across 8 16B slots ->
// balanced 8-lanes/bank for wave64 ds_read_b128 (minimum, conflict-free).
__device__ inline int swz_chunk(int row, int d8) {
  return row * 32 + (d8 ^ (row & 7));
}

// -------- single kernel: 512 blocks = b(16) x jblk(4: 64j) x mg(8: 4m) --------
// 4 waves, wave -> own m. R1 skeleton (best: 24.4us), MFMA shape 32x32x16.
__global__ __launch_bounds__(256, 2)
void mp_match_kernel(const float* __restrict__ lt,
                     const float* __restrict__ rt,
                     const float* __restrict__ kern,
                     float* __restrict__ out) {
  __shared__ short lds_rt[64 * 256];   // 32 KB, raw rt bf16, swizzled
  __shared__ short lds_lt[64 * 256];   // 32 KB, lt chunk bf16, swizzled

  const int bid = blockIdx.x;          // 512 blocks
  const int xcd = bid & 7;             // b = xcd or 8+xcd -> L2 locality
  const int idx = bid >> 3;            // 0..63
  const int b   = ((idx >> 5) << 3) | xcd;
  const int rem = idx & 31;
  const int jblk = rem & 3;            // 4 j-blocks of 64
  const int mg   = rem >> 2;           // 8 m-groups of 4
  const int j0   = jblk * 64;

  const int tid  = threadIdx.x;        // 0..255
  const int lane = tid & 63;
  const int w    = tid >> 6;           // wave -> its own m
  const int m    = mg * 4 + w;
  const int l31  = lane & 31;          // 32x32 frag row/col
  const int kh   = lane >> 5;          // k-half selector

  // ---- stage raw rt tile [64 j][256 d] -> bf16 LDS (swizzled) ----
  {
    const float* rbase = rt + ((size_t)b * T2n + j0) * Dn;
    #pragma unroll
    for (int rep = 0; rep < 8; ++rep) {
      int chunk = rep * 256 + tid;     // 0..2047
      int row = chunk >> 5, c = chunk & 31;
      const f32x4* s = reinterpret_cast<const f32x4*>(rbase + row * Dn + c * 8);
      f32x4 f0 = s[0], f1 = s[1];
      short8 v;
      v[0] = f2b(f0.x); v[1] = f2b(f0.y); v[2] = f2b(f0.z); v[3] = f2b(f0.w);
      v[4] = f2b(f1.x); v[5] = f2b(f1.y); v[6] = f2b(f1.z); v[7] = f2b(f1.w);
      *reinterpret_cast<short8*>(&lds_rt[swz_chunk(row, c) * 8]) = v;
    }
  }
  __syncthreads();

  // ---- B fragments (32x32x16): 2 j-frags x 16 k-steps, scaled by k[m] ----
  // B layout: col = lane&31, k = (lane>>5)*8 + e  -> d8 = kstep*2 + kh
  short8 bsc[2][16];                   // 128 VGPR
  {
    const float* kbase = kern + (size_t)m * Dn;
    #pragma unroll
    for (int ks = 0; ks < 16; ++ks) {
      int d8 = ks * 2 + kh;
      const f32x4* kp = reinterpret_cast<const f32x4*>(kbase + d8 * 8);
      f32x4 k0 = kp[0], k1 = kp[1];
      #pragma unroll
      for (int jf = 0; jf < 2; ++jf) {
        int brow = jf * 32 + l31;
        short8 r = *reinterpret_cast<const short8*>(&lds_rt[swz_chunk(brow, d8) * 8]);
        short8 v;
        v[0] = f2b(b2f(r[0]) * k0.x); v[1] = f2b(b2f(r[1]) * k0.y);
        v[2] = f2b(b2f(r[2]) * k0.z); v[3] = f2b(b2f(r[3]) * k0.w);
        v[4] = f2b(b2f(r[4]) * k1.x); v[5] = f2b(b2f(r[5]) * k1.y);
        v[6] = f2b(b2f(r[6]) * k1.z); v[7] = f2b(b2f(r[7]) * k1.w);
        bsc[jf][ks] = v;
      }
    }
  }

  float jmax0 = -1e30f, jmax1 = -1e30f;

  // ---- 4 chunks of 64 i-rows; A-frags: row = it*32 + l31, d8 = ks*2 + kh ----
  for (int ic = 0; ic < 4; ++ic) {
    if (ic) __syncthreads();           // prev compute done before overwrite
    const float* lbase = lt + ((size_t)b * T1n + ic * 64) * Dn;
    #pragma unroll
    for (int rep = 0; rep < 8; ++rep) {
      int chunk = rep * 256 + tid;
      int row = chunk >> 5, c = chunk & 31;
      const f32x4* s = reinterpret_cast<const f32x4*>(lbase + row * Dn + c * 8);
      f32x4 f0 = s[0], f1 = s[1];
      short8 v;
      v[0] = f2b(f0.x); v[1] = f2b(f0.y); v[2] = f2b(f0.z); v[3] = f2b(f0.w);
      v[4] = f2b(f1.x); v[5] = f2b(f1.y); v[6] = f2b(f1.z); v[7] = f2b(f1.w);
      *reinterpret_cast<short8*>(&lds_lt[swz_chunk(row, c) * 8]) = v;
    }
    __syncthreads();

    f32x16 c00 = {}, c01 = {}, c10 = {}, c11 = {};
    #pragma unroll
    for (int ks = 0; ks < 16; ++ks) {
      int d8 = ks * 2 + kh;
      short8 A0 = *reinterpret_cast<const short8*>(&lds_lt[swz_chunk(l31, d8) * 8]);
      short8 A1 = *reinterpret_cast<const short8*>(&lds_lt[swz_chunk(32 + l31, d8) * 8]);
      c00 = __builtin_amdgcn_mfma_f32_32x32x16_bf16(A0, bsc[0][ks], c00, 0, 0, 0);
      c01 = __builtin_amdgcn_mfma_f32_32x32x16_bf16(A0, bsc[1][ks], c01, 0, 0, 0);
      c10 = __builtin_amdgcn_mfma_f32_32x32x16_bf16(A1, bsc[0][ks], c10, 0, 0, 0);
      c11 = __builtin_amdgcn_mfma_f32_32x32x16_bf16(A1, bsc[1][ks], c11, 0, 0, 0);
    }
    // fold 16 acc regs (16 distinct i-rows per lane-half) into running col-max
    #pragma unroll
    for (int r = 0; r < 16; ++r) {
      jmax0 = fmaxf(jmax0, fmaxf(c00[r], c10[r]));
      jmax1 = fmaxf(jmax1, fmaxf(c01[r], c11[r]));
    }
  }

  // ---- combine lane-halves (rows differ, col = lane&31 same), tanh, store ----
  jmax0 = fmaxf(jmax0, __shfl_xor(jmax0, 32));
  jmax1 = fmaxf(jmax1, __shfl_xor(jmax1, 32));
  float v = (lane < 32) ? jmax0 : jmax1;   // jf = lane>>5, col = lane&31
  int j = j0 + lane;                       // jf*32 + l31 == lane
  out[((size_t)b * T2n + j) * MPn + m] = tanhf(v);
}

extern "C" void kernel_launch(void* const* d_in, const int* in_sizes, int n_in,
                              void* d_out, int out_size, void* d_ws, size_t ws_size,
                              hipStream_t stream) {
  const float* lt   = (const float*)d_in[0];
  const float* rt   = (const float*)d_in[1];
  const float* kern = (const float*)d_in[2];
  float* out = (float*)d_out;

  dim3 grid(512);   // b(16) x jblk(4) x mg(8), XCD-swizzled
  dim3 block(256);  // 4 waves, one m per wave
  mp_match_kernel<<<grid, block, 0, stream>>>(lt, rt, kern, out);
}

// Round 8
// 26.566 us; speedup vs baseline: 2.8602x; 1.0089x over previous
//
#include <hip/hip_runtime.h>
#include <hip/hip_bf16.h>
#include <math.h>

#define Bn   16
#define T1n  256
#define T2n  256
#define Dn   256
#define MPn  32

typedef __attribute__((ext_vector_type(8))) short short8;
typedef __attribute__((ext_vector_type(4))) float f32x4;

__device__ inline short f2b(float f) {
  __hip_bfloat16 h = __float2bfloat16(f);
  return __builtin_bit_cast(short, h);
}
__device__ inline float b2f(short s) {
  unsigned int u = ((unsigned int)(unsigned short)s) << 16;
  return __builtin_bit_cast(float, u);
}
__device__ inline float max4(f32x4 a) {
  return fmaxf(fmaxf(a.x, a.y), fmaxf(a.z, a.w));
}

// swizzled 16B-chunk index within a [64 row][256 d] bf16 tile.
// XOR of row&7 spreads stride-512B column reads across 8 16B slots ->
// balanced 8-lanes/bank for wave64 ds_read_b128 (conflict-free minimum).
__device__ inline int swz_chunk(int row, int d8) {
  return row * 32 + (d8 ^ (row & 7));
}

// ---- single kernel: 512 blocks = b(16) x jblk(4: 64j) x mg(8: 4m) ----
// 8 waves of 64; wave w -> (jhalf = w>>2, m = mg*4 + (w&3)); 32 j x 1 m per wave.
// 64 KB LDS + <=128 VGPR  => 2 blocks/CU = 16 waves/CU = 4 waves/SIMD.
__global__ __launch_bounds__(512, 4)
void mp_match_kernel(const float* __restrict__ lt,
                     const float* __restrict__ rt,
                     const float* __restrict__ kern,
                     float* __restrict__ out) {
  __shared__ short lds_rt[64 * 256];   // 32 KB, rt bf16, swizzled
  __shared__ short lds_lt[64 * 256];   // 32 KB, lt chunk bf16, swizzled

  const int bid = blockIdx.x;          // 512 blocks
  const int xcd = bid & 7;             // b = xcd or 8+xcd -> L2 locality
  const int idx = bid >> 3;            // 0..63
  const int b   = ((idx >> 5) << 3) | xcd;
  const int rem = idx & 31;
  const int jblk = rem & 3;            // 4 j-blocks of 64
  const int mg   = rem >> 2;           // 8 m-groups of 4
  const int j0   = jblk * 64;

  const int tid  = threadIdx.x;        // 0..511
  const int lane = tid & 63;
  const int w    = tid >> 6;           // 0..7
  const int m    = mg * 4 + (w & 3);
  const int jh   = w >> 2;             // j-half of the 64-j tile
  const int bl   = lane & 15;
  const int hl   = lane >> 4;

  // ---- stage rt tile [64 j][256 d] -> bf16 LDS (swizzled), 4 reps ----
  {
    const float* rbase = rt + ((size_t)b * T2n + j0) * Dn;
    #pragma unroll
    for (int rep = 0; rep < 4; ++rep) {
      int chunk = rep * 512 + tid;     // 0..2047
      int row = chunk >> 5, c = chunk & 31;
      const f32x4* s = reinterpret_cast<const f32x4*>(rbase + row * Dn + c * 8);
      f32x4 f0 = s[0], f1 = s[1];
      short8 v;
      v[0] = f2b(f0.x); v[1] = f2b(f0.y); v[2] = f2b(f0.z); v[3] = f2b(f0.w);
      v[4] = f2b(f1.x); v[5] = f2b(f1.y); v[6] = f2b(f1.z); v[7] = f2b(f1.w);
      *reinterpret_cast<short8*>(&lds_rt[swz_chunk(row, c) * 8]) = v;
    }
  }
  __syncthreads();

  // ---- B fragments (this wave's 32 j rows), scaled by k[m], in regs ----
  short8 bsc[2][8];                    // 64 VGPR
  {
    const float* kbase = kern + (size_t)m * Dn;
    #pragma unroll
    for (int kk = 0; kk < 8; ++kk) {
      int d8 = kk * 4 + hl;
      const f32x4* kp = reinterpret_cast<const f32x4*>(kbase + d8 * 8);
      f32x4 k0 = kp[0], k1 = kp[1];
      #pragma unroll
      for (int sub = 0; sub < 2; ++sub) {
        int brow = jh * 32 + sub * 16 + bl;
        short8 r = *reinterpret_cast<const short8*>(&lds_rt[swz_chunk(brow, d8) * 8]);
        short8 v;
        v[0] = f2b(b2f(r[0]) * k0.x); v[1] = f2b(b2f(r[1]) * k0.y);
        v[2] = f2b(b2f(r[2]) * k0.z); v[3] = f2b(b2f(r[3]) * k0.w);
        v[4] = f2b(b2f(r[4]) * k1.x); v[5] = f2b(b2f(r[5]) * k1.y);
        v[6] = f2b(b2f(r[6]) * k1.z); v[7] = f2b(b2f(r[7]) * k1.w);
        bsc[sub][kk] = v;
      }
    }
  }

  float jmax0 = -1e30f, jmax1 = -1e30f;

  // ---- 4 chunks of 64 i-rows; every wave consumes ALL i for its (jh, m) ----
  for (int ic = 0; ic < 4; ++ic) {
    if (ic) __syncthreads();           // prev compute done before overwrite
    const float* lbase = lt + ((size_t)b * T1n + ic * 64) * Dn;
    #pragma unroll
    for (int rep = 0; rep < 4; ++rep) {
      int chunk = rep * 512 + tid;
      int row = chunk >> 5, c = chunk & 31;
      const f32x4* s = reinterpret_cast<const f32x4*>(lbase + row * Dn + c * 8);
      f32x4 f0 = s[0], f1 = s[1];
      short8 v;
      v[0] = f2b(f0.x); v[1] = f2b(f0.y); v[2] = f2b(f0.z); v[3] = f2b(f0.w);
      v[4] = f2b(f1.x); v[5] = f2b(f1.y); v[6] = f2b(f1.z); v[7] = f2b(f1.w);
      *reinterpret_cast<short8*>(&lds_lt[swz_chunk(row, c) * 8]) = v;
    }
    __syncthreads();

    #pragma unroll
    for (int it2 = 0; it2 < 4; ++it2) {
      int arow = it2 * 16 + bl;
      f32x4 a0 = {0.f, 0.f, 0.f, 0.f};
      f32x4 a1 = {0.f, 0.f, 0.f, 0.f};
      #pragma unroll
      for (int kk = 0; kk < 8; ++kk) {
        short8 A = *reinterpret_cast<const short8*>(
            &lds_lt[swz_chunk(arow, kk * 4 + hl) * 8]);
        a0 = __builtin_amdgcn_mfma_f32_16x16x32_bf16(A, bsc[0][kk], a0, 0, 0, 0);
        a1 = __builtin_amdgcn_mfma_f32_16x16x32_bf16(A, bsc[1][kk], a1, 0, 0, 0);
      }
      jmax0 = fmaxf(jmax0, max4(a0));
      jmax1 = fmaxf(jmax1, max4(a1));
    }
  }

  // ---- cross-lane col-max over the 4 row-groups, tanh, store ----
  jmax0 = fmaxf(jmax0, __shfl_xor(jmax0, 16));
  jmax0 = fmaxf(jmax0, __shfl_xor(jmax0, 32));
  jmax1 = fmaxf(jmax1, __shfl_xor(jmax1, 16));
  jmax1 = fmaxf(jmax1, __shfl_xor(jmax1, 32));
  if (hl < 2) {
    float v = hl ? jmax1 : jmax0;
    int j = j0 + jh * 32 + hl * 16 + bl;
    out[((size_t)b * T2n + j) * MPn + m] = tanhf(v);
  }
}

extern "C" void kernel_launch(void* const* d_in, const int* in_sizes, int n_in,
                              void* d_out, int out_size, void* d_ws, size_t ws_size,
                              hipStream_t stream) {
  const float* lt   = (const float*)d_in[0];
  const float* rt   = (const float*)d_in[1];
  const float* kern = (const float*)d_in[2];
  float* out = (float*)d_out;

  dim3 grid(512);   // b(16) x jblk(4) x mg(8), XCD-swizzled
  dim3 block(512);  // 8 waves: (jhalf, m) per wave -> 4 waves/SIMD resident
  mp_match_kernel<<<grid, block, 0, stream>>>(lt, rt, kern, out);
}